// Round 1
// baseline (620.864 us; speedup 1.0000x reference)
//
#include <hip/hip_runtime.h>
#include <hip/hip_bf16.h>

typedef __attribute__((ext_vector_type(4))) float f32x4;
typedef __attribute__((ext_vector_type(4))) int   i32x4;
typedef __attribute__((ext_vector_type(8))) short s16x8;
typedef __attribute__((ext_vector_type(4))) unsigned short u16x4;

#define T_ 512
#define B_ 8
#define H_ 128
#define V_ 32000
#define M_ 4096   // T_*B_

// round-to-nearest-even f32 -> bf16 (inputs are finite)
__device__ __forceinline__ unsigned short f2b(float f) {
  unsigned int u = __float_as_uint(f);
  u = (u + 0x7FFFu + ((u >> 16) & 1u)) >> 16;
  return (unsigned short)u;
}

// ---------------- fc_W f32 -> bf16 ----------------
__global__ __launch_bounds__(256) void convert_w_kernel(const float* __restrict__ src,
                                                        unsigned short* __restrict__ dst, int n4) {
  int idx = blockIdx.x * 256 + threadIdx.x;
  int stride = gridDim.x * 256;
  for (int c = idx; c < n4; c += stride) {
    f32x4 v = ((const f32x4*)src)[c];
    u16x4 o;
    o.x = f2b(v.x); o.y = f2b(v.y); o.z = f2b(v.z); o.w = f2b(v.w);
    ((u16x4*)dst)[c] = o;
  }
}

// ---------------- pre = in @ W_ih^T + b_ih + b_hh ----------------
// Row m = t*8+b of output [T,B,H]. GATHER: input row = embedding[x[b,t]].
// 128 threads: thread i holds W row i in 32 f32x4 regs; input row broadcast via LDS.
template<bool GATHER>
__global__ __launch_bounds__(128) void pre_kernel(const float* __restrict__ src,
                                                  const int* __restrict__ x,
                                                  const float* __restrict__ W,
                                                  const float* __restrict__ b1,
                                                  const float* __restrict__ b2,
                                                  float* __restrict__ out) {
  const int tid = threadIdx.x;
  __shared__ alignas(16) float lds_in[H_];
  f32x4 w[32];
#pragma unroll
  for (int r = 0; r < 32; ++r) w[r] = *(const f32x4*)(W + tid * H_ + 4 * r);
  const float bsum = b1[tid] + b2[tid];
  const int m0 = blockIdx.x * 16;

  auto src_row = [&](int m) -> const float* {
    if (GATHER) {
      int t = m >> 3, b = m & 7;
      int tok = x[(b << 9) + t];          // x is [B,T]
      return src + (size_t)tok * H_;
    } else {
      return src + (size_t)m * H_;
    }
  };

  float stage = src_row(m0)[tid];
  for (int rr = 0; rr < 16; ++rr) {
    const int m = m0 + rr;
    lds_in[tid] = stage;
    __syncthreads();
    if (rr + 1 < 16) stage = src_row(m0 + rr + 1)[tid];  // prefetch next row
    f32x4 acc4 = {0.f, 0.f, 0.f, 0.f};
#pragma unroll
    for (int r = 0; r < 32; ++r) {
      f32x4 hv = *(const f32x4*)(lds_in + 4 * r);
      acc4 += hv * w[r];
    }
    out[m * H_ + tid] = acc4.x + acc4.y + acc4.z + acc4.w + bsum;
    __syncthreads();
  }
}

// ---------------- sequential scan: h = tanh(pre[t] + h @ W_hh^T) ----------------
// one block per batch; 512 threads: q=tid>>7 (K-slice), i=tid&127 (output unit).
// thread holds W_hh[i][q*32 .. q*32+31] in 8 f32x4 regs.
template<bool BF16OUT>
__global__ __launch_bounds__(512) void scan_kernel(const float* __restrict__ pre,
                                                   const float* __restrict__ W_hh,
                                                   void* __restrict__ h_out) {
  const int b = blockIdx.x;
  const int tid = threadIdx.x;
  const int q = tid >> 7;
  const int i = tid & 127;
  __shared__ alignas(16) float h_lds[H_];
  __shared__ float part[3 * H_];

  f32x4 w[8];
  const float* wrow = W_hh + i * H_ + q * 32;
#pragma unroll
  for (int r = 0; r < 8; ++r) w[r] = *(const f32x4*)(wrow + 4 * r);

  if (tid < H_) h_lds[tid] = 0.f;
  float pre_cur = 0.f;
  if (q == 0) pre_cur = pre[(b << 7) + i];   // t = 0
  __syncthreads();

  for (int t = 0; t < T_; ++t) {
    float pre_next = 0.f;
    if (q == 0 && t + 1 < T_) pre_next = pre[(((t + 1) * B_ + b) << 7) + i];  // prefetch
    f32x4 acc4 = {0.f, 0.f, 0.f, 0.f};
#pragma unroll
    for (int r = 0; r < 8; ++r) {
      f32x4 hv = *(const f32x4*)(h_lds + q * 32 + 4 * r);
      acc4 += hv * w[r];
    }
    float acc = acc4.x + acc4.y + acc4.z + acc4.w;
    if (q > 0) part[(q - 1) * H_ + i] = acc;
    __syncthreads();
    if (q == 0) {
      float val = acc + part[i] + part[H_ + i] + part[2 * H_ + i] + pre_cur;
      // tanh(x) = 1 - 2/(exp(2x)+1)   (native exp/rcp, ~1e-6 abs err)
      float e = __expf(2.f * val);
      float h = 1.f - 2.f * __builtin_amdgcn_rcpf(e + 1.f);
      h_lds[i] = h;
      const int gi = ((t * B_ + b) << 7) + i;
      if (BF16OUT) ((unsigned short*)h_out)[gi] = f2b(h);
      else         ((float*)h_out)[gi] = h;
      pre_cur = pre_next;
    }
    __syncthreads();
  }
}

// ---------------- logits = h1 @ fc_W^T + fc_b  (bf16 MFMA) ----------------
// A = h1b [4096][128] bf16 row-major, B = fcWb [32000][128] bf16 row-major.
// 128x128 tile per block, 4 waves each compute a 64x64 quadrant (4x4 MFMA frags, K=4x32).
// LDS XOR-swizzle (cc ^= row&7 on 16B chunks) kills stride-256B bank conflicts.
__device__ __forceinline__ int swz(int row, int cc) {
  return row * 256 + ((cc ^ (row & 7)) << 4);
}

__global__ __launch_bounds__(256) void final_gemm(const unsigned short* __restrict__ A,
                                                  const unsigned short* __restrict__ Bw,
                                                  const float* __restrict__ bias,
                                                  float* __restrict__ out) {
  __shared__ alignas(16) char smem[65536];   // A tile [0,32K), B tile [32K,64K)
  const int tid = threadIdx.x;
  const int bid = blockIdx.x;
  const int mt = bid & 31, nt = bid >> 5;    // 32 m-tiles, 250 n-tiles
  const int m0 = mt << 7, v0 = nt << 7;
  const int lane = tid & 63, wv = tid >> 6;
  const int wm = wv >> 1, wn = wv & 1;

  // stage A and B tiles (each 32KB, contiguous in global since K=full row)
  const char* gA = (const char*)A + (size_t)m0 * 256;
  const char* gB = (const char*)Bw + (size_t)v0 * 256;
#pragma unroll
  for (int it = 0; it < 8; ++it) {
    int c = it * 256 + tid;
    i32x4 va = *(const i32x4*)(gA + c * 16);
    *(i32x4*)(smem + swz(c >> 4, c & 15)) = va;
  }
#pragma unroll
  for (int it = 0; it < 8; ++it) {
    int c = it * 256 + tid;
    i32x4 vb = *(const i32x4*)(gB + c * 16);
    *(i32x4*)(smem + 32768 + swz(c >> 4, c & 15)) = vb;
  }
  __syncthreads();

  f32x4 acc[4][4] = {};
  const int l15 = lane & 15, lg = lane >> 4;
#pragma unroll
  for (int kk = 0; kk < 4; ++kk) {
    const int cc = kk * 4 + lg;
    s16x8 a[4], bf[4];
#pragma unroll
    for (int mi = 0; mi < 4; ++mi) {
      int row = wm * 64 + mi * 16 + l15;
      a[mi] = *(const s16x8*)(smem + swz(row, cc));
    }
#pragma unroll
    for (int ni = 0; ni < 4; ++ni) {
      int row = wn * 64 + ni * 16 + l15;
      bf[ni] = *(const s16x8*)(smem + 32768 + swz(row, cc));
    }
#pragma unroll
    for (int mi = 0; mi < 4; ++mi)
#pragma unroll
      for (int ni = 0; ni < 4; ++ni)
        acc[mi][ni] = __builtin_amdgcn_mfma_f32_16x16x32_bf16(a[mi], bf[ni], acc[mi][ni], 0, 0, 0);
  }

  // epilogue: D lane map col=lane&15, row=(lane>>4)*4+reg. out is [B,T,V], m = t*8+b.
#pragma unroll
  for (int ni = 0; ni < 4; ++ni) {
    const int v = v0 + wn * 64 + ni * 16 + l15;
    const float bv = bias[v];
#pragma unroll
    for (int mi = 0; mi < 4; ++mi) {
#pragma unroll
      for (int r = 0; r < 4; ++r) {
        int m = m0 + wm * 64 + mi * 16 + (lg << 2) + r;
        int orow = ((m & 7) << 9) | (m >> 3);          // b*T + t
        out[(size_t)orow * V_ + v] = acc[mi][ni][r] + bv;
      }
    }
  }
}

extern "C" void kernel_launch(void* const* d_in, const int* in_sizes, int n_in,
                              void* d_out, int out_size, void* d_ws, size_t ws_size,
                              hipStream_t stream) {
  const int*   x     = (const int*)d_in[0];
  const float* emb   = (const float*)d_in[1];
  const float* W_ih0 = (const float*)d_in[2];
  const float* W_hh0 = (const float*)d_in[3];
  const float* b_ih0 = (const float*)d_in[4];
  const float* b_hh0 = (const float*)d_in[5];
  const float* W_ih1 = (const float*)d_in[6];
  const float* W_hh1 = (const float*)d_in[7];
  const float* b_ih1 = (const float*)d_in[8];
  const float* b_hh1 = (const float*)d_in[9];
  const float* fc_W  = (const float*)d_in[10];
  const float* fc_b  = (const float*)d_in[11];
  float* out = (float*)d_out;

  char* ws = (char*)d_ws;
  float*          pre  = (float*)ws;                          // 2 MB
  float*          h0   = (float*)(ws + (2u << 20));           // 2 MB
  unsigned short* h1b  = (unsigned short*)(ws + (4u << 20));  // 1 MB
  unsigned short* fcWb = (unsigned short*)(ws + (5u << 20));  // 8 MB

  // fc_W -> bf16 (independent; overlaps nothing but cheap)
  convert_w_kernel<<<1024, 256, 0, stream>>>(fc_W, fcWb, V_ * H_ / 4);

  // layer 0
  pre_kernel<true><<<256, 128, 0, stream>>>(emb, x, W_ih0, b_ih0, b_hh0, pre);
  scan_kernel<false><<<B_, 512, 0, stream>>>(pre, W_hh0, (void*)h0);

  // layer 1
  pre_kernel<false><<<256, 128, 0, stream>>>(h0, nullptr, W_ih1, b_ih1, b_hh1, pre);
  scan_kernel<true><<<B_, 512, 0, stream>>>(pre, W_hh1, (void*)h1b);

  // logits
  final_gemm<<<32 * 250, 256, 0, stream>>>(h1b, fcWb, fc_b, out);
}